// Round 1
// baseline (5522.790 us; speedup 1.0000x reference)
//
#include <hip/hip_runtime.h>
#include <math.h>

// Problem constants
#define S_   56
#define B_   32
#define C_   1024
#define T_   48
#define TS   47      // T-1 decode steps
#define H_   1024
#define EMB_ 512
#define RANK_ 128
#define VOCAB_ 32000
#define G4   4096    // 4*H

__device__ __forceinline__ float sigmoidf_(float x){ return 1.0f/(1.0f+expf(-x)); }

// ---------- init: h0,h1 <- encoder_state ; c0,c1,ctx <- 0 ----------
__global__ void k_init(const float* __restrict__ es, float* h0, float* h1,
                       float* c0, float* c1, float* ctx){
  int i = blockIdx.x*blockDim.x + threadIdx.x;
  if (i < 32*H_){ h0[i]=es[i]; h1[i]=es[32*H_+i]; c0[i]=0.f; c1[i]=0.f; ctx[i]=0.f; }
}

// ---------- embedding: emb[t*32+b][0:512] = E[tok[b,t]] @ P ----------
__global__ void k_embed(const float* __restrict__ E, const float* __restrict__ P,
                        const int* __restrict__ tok, float* __restrict__ emb){
  int blk = blockIdx.x;            // t*32+b  (1504 blocks, 128 threads)
  int t = blk >> 5, b = blk & 31, tid = threadIdx.x;
  __shared__ float er[RANK_];
  int tk = tok[b*T_ + t];
  er[tid] = E[(size_t)tk*RANK_ + tid];
  __syncthreads();
  float4 acc = {0.f,0.f,0.f,0.f};
  int e = tid*4;
  for (int r2 = 0; r2 < RANK_; r2++){
    float ev = er[r2];
    float4 p = *(const float4*)(P + (size_t)r2*EMB_ + e);
    acc.x += ev*p.x; acc.y += ev*p.y; acc.z += ev*p.z; acc.w += ev*p.w;
  }
  *(float4*)(emb + (size_t)blk*EMB_ + e) = acc;
}

// ---------- concat xcat[b][0:512]=emb(t), [512:1536]=ctx ----------
__global__ void k_concat(const float* __restrict__ emb, const float* __restrict__ ctx,
                         float* __restrict__ xcat, int t){
  int i = blockIdx.x*blockDim.x + threadIdx.x;   // 32*1536
  int b = i / 1536, k = i % 1536;
  xcat[i] = (k < 512) ? emb[((size_t)t*32 + b)*EMB_ + k] : ctx[b*C_ + (k-512)];
}

// ---------- gates GEMM: partial[ch][32][4096] = (X1@W | X2@U) k-chunk ----------
// K = K1 + K2 split in 256-wide chunks (K1 % 256 == 0). N-tile 256, M = 32.
__global__ void k_gemm2(const float* __restrict__ X1, const float* __restrict__ W, int K1,
                        const float* __restrict__ X2, const float* __restrict__ U, int K2,
                        float* __restrict__ partial){
  int jt = blockIdx.x;     // 16 tiles of 256 cols
  int ch = blockIdx.y;     // k-chunk index
  int tid = threadIdx.x;   // 256
  int gk0 = ch*256;
  const float* Xsrc; const float* Wsrc; int xlen;
  if (gk0 < K1){ Xsrc = X1; Wsrc = W + (size_t)gk0*G4; xlen = K1; }
  else         { Xsrc = X2; Wsrc = U + (size_t)(gk0-K1)*G4; xlen = K2; gk0 -= K1; }

  __shared__ float Xs[32][36];       // [b][k], stride 36 -> bank (4b+k)%32
  __shared__ float Ws[32*256];       // [k][j]
  int jg = tid & 63, bg = tid >> 6;  // 4 j per thread, 8 b per thread
  float4 acc[8];
  #pragma unroll
  for (int i=0;i<8;i++) acc[i] = make_float4(0.f,0.f,0.f,0.f);

  for (int sc = 0; sc < 8; sc++){
    { // stage X 32b x 32k
      int b = tid & 31, kq = tid >> 5;
      float4 v = *(const float4*)(Xsrc + (size_t)b*xlen + gk0 + sc*32 + kq*4);
      *(float4*)(&Xs[b][kq*4]) = v;
    }
    #pragma unroll
    for (int i2 = 0; i2 < 8; i2++){   // stage W 32k x 256j
      int idx = i2*256 + tid;
      int k = idx >> 6, jq = idx & 63;
      *(float4*)(&Ws[k*256 + jq*4]) =
        *(const float4*)(Wsrc + (size_t)(sc*32 + k)*G4 + jt*256 + jq*4);
    }
    __syncthreads();
    #pragma unroll
    for (int k = 0; k < 32; k++){
      float4 w4 = *(const float4*)(&Ws[k*256 + jg*4]);
      #pragma unroll
      for (int i = 0; i < 8; i++){
        float xv = Xs[bg*8 + i][k];
        acc[i].x += xv*w4.x; acc[i].y += xv*w4.y;
        acc[i].z += xv*w4.z; acc[i].w += xv*w4.w;
      }
    }
    __syncthreads();
  }
  #pragma unroll
  for (int i = 0; i < 8; i++){
    int b = bg*8 + i;
    *(float4*)(partial + ((size_t)ch*32 + b)*G4 + jt*256 + jg*4) = acc[i];
  }
}

// ---------- LSTM cell: sum partials + bias -> gates -> update c,h ----------
__global__ void k_cell(const float* __restrict__ partial, int nch,
                       const float* __restrict__ bias,
                       float* __restrict__ c, float* __restrict__ h,
                       float* __restrict__ feats, int t){
  int i = blockIdx.x*blockDim.x + threadIdx.x;    // 32*1024
  int b = i >> 10, j = i & 1023;
  float gi = bias[j], gf = bias[j+1024], gg = bias[j+2048], go = bias[j+3072];
  for (int cc = 0; cc < nch; cc++){
    const float* p = partial + ((size_t)cc*32 + b)*G4;
    gi += p[j]; gf += p[j+1024]; gg += p[j+2048]; go += p[j+3072];
  }
  float ii = sigmoidf_(gi), ff = sigmoidf_(gf), g = tanhf(gg), oo = sigmoidf_(go);
  float cn = ff*c[i] + ii*g;
  float hn = oo*tanhf(cn);
  c[i] = cn; h[i] = hn;
  if (feats) feats[((size_t)t*32 + b)*2048 + j] = hn;
}

// ---------- attention: scores -> masked softmax -> context ----------
__global__ void k_attn(const float* __restrict__ enc, const int* __restrict__ enc_lens,
                       const float* __restrict__ h1, float* __restrict__ ctx,
                       float* __restrict__ feats, int t){
  int b = blockIdx.x, tid = threadIdx.x;   // 32 blocks x 256
  __shared__ float hS[C_];
  __shared__ float sS[64];
  __shared__ float pS[64];
  #pragma unroll
  for (int i=0;i<4;i++) hS[tid + i*256] = h1[b*C_ + tid + i*256];
  __syncthreads();
  int wv = tid >> 6, lane = tid & 63;
  for (int s = wv; s < S_; s += 4){
    const float* er = enc + ((size_t)s*32 + b)*C_;
    float a = 0.f;
    for (int k = lane*4; k < C_; k += 256){
      float4 e = *(const float4*)(er + k);
      a += e.x*hS[k] + e.y*hS[k+1] + e.z*hS[k+2] + e.w*hS[k+3];
    }
    #pragma unroll
    for (int off=32; off>0; off>>=1) a += __shfl_down(a, off);
    if (lane == 0) sS[s] = a;
  }
  __syncthreads();
  if (tid < 64){
    int len = enc_lens[b];
    float sc = (tid < len) ? sS[tid] : -1e30f;
    float m = sc;
    #pragma unroll
    for (int off=32; off>0; off>>=1) m = fmaxf(m, __shfl_xor(m, off));
    float e = expf(sc - m);
    float ssum = e;
    #pragma unroll
    for (int off=32; off>0; off>>=1) ssum += __shfl_xor(ssum, off);
    pS[tid] = e / ssum;
  }
  __syncthreads();
  for (int c2 = tid; c2 < C_; c2 += 256){
    float a = 0.f;
    for (int s2 = 0; s2 < S_; s2++) a += pS[s2] * enc[((size_t)s2*32 + b)*C_ + c2];
    ctx[b*C_ + c2] = a;
    feats[((size_t)t*32 + b)*2048 + 1024 + c2] = a;
  }
}

// ---------- hproj = tanh(feats @ Wo + bo) : [1504,2048]x[2048,512] ----------
__global__ void k_hproj(const float* __restrict__ feats, const float* __restrict__ Wo,
                        const float* __restrict__ bo, float* __restrict__ hp){
  int nt = blockIdx.x, jt = blockIdx.y, tid = threadIdx.x;  // (47,4) x 256
  __shared__ float Fs[32][36];
  __shared__ float Ws[32*128];
  int jg = tid & 31, bg = tid >> 5;   // 4 j, 4 b per thread
  float4 acc[4];
  #pragma unroll
  for (int i=0;i<4;i++) acc[i] = make_float4(0.f,0.f,0.f,0.f);
  for (int kc = 0; kc < 2048; kc += 32){
    { int b = tid & 31, kq = tid >> 5;
      *(float4*)(&Fs[b][kq*4]) =
        *(const float4*)(feats + ((size_t)nt*32 + b)*2048 + kc + kq*4); }
    #pragma unroll
    for (int i2=0;i2<4;i2++){
      int idx = i2*256 + tid;
      int k = idx >> 5, jq = idx & 31;
      *(float4*)(&Ws[k*128 + jq*4]) =
        *(const float4*)(Wo + (size_t)(kc + k)*EMB_ + jt*128 + jq*4);
    }
    __syncthreads();
    #pragma unroll
    for (int k=0;k<32;k++){
      float4 w4 = *(const float4*)(&Ws[k*128 + jg*4]);
      #pragma unroll
      for (int i=0;i<4;i++){
        float xv = Fs[bg*4 + i][k];
        acc[i].x += xv*w4.x; acc[i].y += xv*w4.y;
        acc[i].z += xv*w4.z; acc[i].w += xv*w4.w;
      }
    }
    __syncthreads();
  }
  float4 b4 = *(const float4*)(bo + jt*128 + jg*4);
  #pragma unroll
  for (int i=0;i<4;i++){
    int b = bg*4 + i;
    float4 v;
    v.x = tanhf(acc[i].x + b4.x); v.y = tanhf(acc[i].y + b4.y);
    v.z = tanhf(acc[i].z + b4.z); v.w = tanhf(acc[i].w + b4.w);
    *(float4*)(hp + ((size_t)nt*32 + b)*EMB_ + jt*128 + jg*4) = v;
  }
}

// ---------- r = hproj @ P^T : [1504,512]x[512,128] ----------
__global__ void k_rproj(const float* __restrict__ hp, const float* __restrict__ P,
                        float* __restrict__ r){
  int n = blockIdx.x, tid = threadIdx.x;   // 1504 x 128
  __shared__ float hS[EMB_];
  *(float4*)(hS + tid*4) = *(const float4*)(hp + (size_t)n*EMB_ + tid*4);
  __syncthreads();
  float a = 0.f;
  for (int e = 0; e < EMB_; e += 4){
    float4 p4 = *(const float4*)(P + (size_t)tid*EMB_ + e);
    a += p4.x*hS[e] + p4.y*hS[e+1] + p4.z*hS[e+2] + p4.w*hS[e+3];
  }
  r[(size_t)n*RANK_ + tid] = a;
}

// ---------- vocab GEMM + online LSE partials; label logit capture ----------
// grid (47 n-tiles, 125 v-chunks of 256), block 256.
__global__ void k_vocab(const float* __restrict__ r, const float* __restrict__ E,
                        const int* __restrict__ tok,
                        float* __restrict__ mpart, float* __restrict__ lpart,
                        float* __restrict__ lablog){
  int nt = blockIdx.x, vc = blockIdx.y, tid = threadIdx.x;
  __shared__ float rS[32][132];        // [n][k], bank (4n+k)%32
  __shared__ float eS[16*260];         // [k][v] transposed E chunk; reused for reduce
  #pragma unroll
  for (int i=0;i<4;i++){               // stage r tile 32x128
    int idx = i*256 + tid; int nl = idx >> 5, kq = idx & 31;
    *(float4*)(&rS[nl][kq*4]) = *(const float4*)(r + ((size_t)nt*32 + nl)*RANK_ + kq*4);
  }
  int ng = tid & 3, vg = tid >> 2;     // 8 n-rows, 4 v-cols per thread
  float acc[8][4];
  #pragma unroll
  for (int i=0;i<8;i++)
    #pragma unroll
    for (int j=0;j<4;j++) acc[i][j] = 0.f;
  int vbase = vc*256;
  for (int kc = 0; kc < 8; kc++){
    __syncthreads();
    #pragma unroll
    for (int i=0;i<4;i++){             // stage E^T [16k][256v]
      int idx = i*256 + tid; int vl = idx >> 2, kq = idx & 3;
      float4 ev = *(const float4*)(E + (size_t)(vbase + vl)*RANK_ + kc*16 + kq*4);
      eS[(kq*4+0)*260 + vl] = ev.x;
      eS[(kq*4+1)*260 + vl] = ev.y;
      eS[(kq*4+2)*260 + vl] = ev.z;
      eS[(kq*4+3)*260 + vl] = ev.w;
    }
    __syncthreads();
    #pragma unroll
    for (int k=0;k<16;k++){
      float4 e4 = *(const float4*)(&eS[k*260 + vg*4]);
      int gk = kc*16 + k;
      #pragma unroll
      for (int i=0;i<8;i++){
        float rv = rS[ng*8 + i][gk];
        acc[i][0] += rv*e4.x; acc[i][1] += rv*e4.y;
        acc[i][2] += rv*e4.z; acc[i][3] += rv*e4.w;
      }
    }
  }
  __syncthreads();
  float* mred = eS;                    // [32][65]
  float* lred = eS + 2080;             // [32][65]
  #pragma unroll
  for (int i=0;i<8;i++){
    int nl = ng*8 + i;
    int n = nt*32 + nl;
    int lbl = tok[nl*T_ + nt + 1];     // b = nl, t = nt
    float m = fmaxf(fmaxf(acc[i][0], acc[i][1]), fmaxf(acc[i][2], acc[i][3]));
    float l = expf(acc[i][0]-m) + expf(acc[i][1]-m) + expf(acc[i][2]-m) + expf(acc[i][3]-m);
    int lo = lbl - (vbase + vg*4);
    if (lo >= 0 && lo < 4) lablog[n] = acc[i][lo];
    mred[nl*65 + vg] = m;
    lred[nl*65 + vg] = l;
  }
  __syncthreads();
  if (tid < 32){
    float M = -1e30f;
    for (int v=0; v<64; v++) M = fmaxf(M, mred[tid*65 + v]);
    float L = 0.f;
    for (int v=0; v<64; v++) L += lred[tid*65 + v]*expf(mred[tid*65 + v] - M);
    int n = nt*32 + tid;
    mpart[(size_t)n*125 + vc] = M;
    lpart[(size_t)n*125 + vc] = L;
  }
}

// ---------- final loss reduction ----------
__global__ void k_loss(const float* __restrict__ mpart, const float* __restrict__ lpart,
                       const float* __restrict__ lablog, const int* __restrict__ tgt_lens,
                       float* __restrict__ out){
  int tid = threadIdx.x;   // 1 block x 256
  float local = 0.f;
  for (int n = tid; n < TS*32; n += 256){
    int t = n >> 5, b = n & 31;
    if (t < tgt_lens[b] - 1){
      const float* mp = mpart + (size_t)n*125;
      const float* lp = lpart + (size_t)n*125;
      float M = -1e30f;
      for (int c2=0;c2<125;c2++) M = fmaxf(M, mp[c2]);
      float L = 0.f;
      for (int c2=0;c2<125;c2++) L += lp[c2]*expf(mp[c2] - M);
      local += (M + logf(L)) - lablog[n];
    }
  }
  __shared__ float red[256];
  red[tid] = local; __syncthreads();
  for (int s2 = 128; s2 > 0; s2 >>= 1){
    if (tid < s2) red[tid] += red[tid + s2];
    __syncthreads();
  }
  if (tid == 0) out[0] = red[0];
}

extern "C" void kernel_launch(void* const* d_in, const int* in_sizes, int n_in,
                              void* d_out, int out_size, void* d_ws, size_t ws_size,
                              hipStream_t stream){
  const float* enc      = (const float*)d_in[0];   // [56,32,1024]
  const float* es       = (const float*)d_in[1];   // [2,32,1024]
  const int*   tok      = (const int*)  d_in[2];   // [32,48]
  const int*   enc_lens = (const int*)  d_in[3];   // [32]
  const int*   tgt_lens = (const int*)  d_in[4];   // [32]
  const float* E        = (const float*)d_in[5];   // [32000,128]
  const float* P        = (const float*)d_in[6];   // [128,512]
  const float* W0       = (const float*)d_in[7];   // [1536,4096]
  const float* U0       = (const float*)d_in[8];   // [1024,4096]
  const float* b0       = (const float*)d_in[9];   // [4096]
  const float* W1       = (const float*)d_in[10];  // [1024,4096]
  const float* U1       = (const float*)d_in[11];  // [1024,4096]
  const float* b1       = (const float*)d_in[12];  // [4096]
  const float* Wo       = (const float*)d_in[13];  // [2048,512]
  const float* bo       = (const float*)d_in[14];  // [512]
  float* out = (float*)d_out;

  float* Wk = (float*)d_ws;
  size_t o = 0;
  float* emb   = Wk + o; o += (size_t)TS*32*EMB_;       // 770048
  float* feats = Wk + o; o += (size_t)TS*32*2048;       // 3080192
  float* hp    = Wk + o; o += (size_t)TS*32*EMB_;       // 770048
  float* r     = Wk + o; o += (size_t)TS*32*RANK_;      // 192512
  float* xcat  = Wk + o; o += (size_t)32*1536;          // 49152
  float* part  = Wk + o; o += (size_t)10*32*G4;         // 1310720
  float* h0    = Wk + o; o += 32*H_;
  float* c0    = Wk + o; o += 32*H_;
  float* h1    = Wk + o; o += 32*H_;
  float* c1    = Wk + o; o += 32*H_;
  float* ctx   = Wk + o; o += 32*H_;
  float* mpart = Wk + o; o += (size_t)TS*32*125;
  float* lpart = Wk + o; o += (size_t)TS*32*125;
  float* lab   = Wk + o; o += (size_t)TS*32;
  // total ~26.9 MB of workspace

  k_init<<<128, 256, 0, stream>>>(es, h0, h1, c0, c1, ctx);
  k_embed<<<TS*32, 128, 0, stream>>>(E, P, tok, emb);

  for (int t = 0; t < TS; t++){
    k_concat<<<192, 256, 0, stream>>>(emb, ctx, xcat, t);
    k_gemm2<<<dim3(16,10), 256, 0, stream>>>(xcat, W0, 1536, h0, U0, 1024, part);
    k_cell<<<128, 256, 0, stream>>>(part, 10, b0, c0, h0, (float*)nullptr, t);
    k_gemm2<<<dim3(16,8), 256, 0, stream>>>(h0, W1, 1024, h1, U1, 1024, part);
    k_cell<<<128, 256, 0, stream>>>(part, 8, b1, c1, h1, feats, t);
    k_attn<<<32, 256, 0, stream>>>(enc, enc_lens, h1, ctx, feats, t);
  }

  k_hproj<<<dim3(TS,4), 256, 0, stream>>>(feats, Wo, bo, hp);
  k_rproj<<<TS*32, 128, 0, stream>>>(hp, P, r);
  k_vocab<<<dim3(TS,125), 256, 0, stream>>>(r, E, tok, mpart, lpart, lab);
  k_loss<<<1, 256, 0, stream>>>(mpart, lpart, lab, tgt_lens, out);
}

// Round 2
// 3328.354 us; speedup vs baseline: 1.6593x; 1.6593x over previous
//
#include <hip/hip_runtime.h>
#include <math.h>

#define S_   56
#define B_   32
#define C_   1024
#define T_   48
#define TS   47
#define H_   1024
#define EMB_ 512
#define RANK_ 128
#define VOCAB_ 32000
#define G4   4096

using bf16x8 = __attribute__((ext_vector_type(8))) __bf16;
using f32x4  = __attribute__((ext_vector_type(4))) float;

__device__ __forceinline__ float sigmoidf_(float x){ return 1.0f/(1.0f+expf(-x)); }
__device__ __forceinline__ float b2f(__bf16 x){ return (float)x; }

// ---------- init: h-sections of xa buffers from encoder_state; c,ctx zero ----------
__global__ void k_init(const float* __restrict__ es, __bf16* xa0a, __bf16* xa1a,
                       float* c0, float* c1){
  int i = blockIdx.x*blockDim.x + threadIdx.x;
  if (i < 32*H_){
    int b = i >> 10, j = i & 1023;
    xa0a[(size_t)b*2560 + 1536 + j] = (__bf16)es[i];           // h0 <- es[0]
    xa0a[(size_t)b*2560 + 512  + j] = (__bf16)0.0f;            // ctx = 0
    xa1a[(size_t)b*2048 + 1024 + j] = (__bf16)es[32*H_ + i];   // h1 <- es[1]
    c0[i] = 0.f; c1[i] = 0.f;
  }
}

// ---------- enc fp32 -> bf16 ----------
__global__ void k_cvt(const float* __restrict__ src, __bf16* __restrict__ dst, int n){
  int i = (blockIdx.x*blockDim.x + threadIdx.x)*4;
  if (i < n){
    float4 v = *(const float4*)(src + i);
    dst[i+0]=(__bf16)v.x; dst[i+1]=(__bf16)v.y; dst[i+2]=(__bf16)v.z; dst[i+3]=(__bf16)v.w;
  }
}

// ---------- embedding: embb[t*32+b][:] = bf16(E[tok[b,t]] @ P); t==0 also into xa0 ----------
__global__ void k_embed(const float* __restrict__ E, const float* __restrict__ P,
                        const int* __restrict__ tok, __bf16* __restrict__ embb,
                        __bf16* __restrict__ xa0a){
  int blk = blockIdx.x;            // t*32+b
  int t = blk >> 5, b = blk & 31, tid = threadIdx.x;   // 128 threads
  __shared__ float er[RANK_];
  int tk = tok[b*T_ + t];
  er[tid] = E[(size_t)tk*RANK_ + tid];
  __syncthreads();
  float4 acc = {0.f,0.f,0.f,0.f};
  int e = tid*4;
  for (int r2 = 0; r2 < RANK_; r2++){
    float ev = er[r2];
    float4 p = *(const float4*)(P + (size_t)r2*EMB_ + e);
    acc.x += ev*p.x; acc.y += ev*p.y; acc.z += ev*p.z; acc.w += ev*p.w;
  }
  size_t o = (size_t)blk*EMB_ + e;
  embb[o+0]=(__bf16)acc.x; embb[o+1]=(__bf16)acc.y;
  embb[o+2]=(__bf16)acc.z; embb[o+3]=(__bf16)acc.w;
  if (t == 0){
    size_t o2 = (size_t)b*2560 + e;
    xa0a[o2+0]=(__bf16)acc.x; xa0a[o2+1]=(__bf16)acc.y;
    xa0a[o2+2]=(__bf16)acc.z; xa0a[o2+3]=(__bf16)acc.w;
  }
}

// ---------- pack [W;U] (row-major fp32 [K][4096]) into MFMA-fragment bf16 tiles ----------
// dst element ((((bi*2+gp)*2+kh)*NCH + ch)*64 + lane)*8 + i  holds  B[k][j] with
// k = kh*KH + ch*32 + (lane>>4)*8 + i,  j = (2*gp + ((lane>>3)&1))*1024 + bi*8 + (lane&7)
__global__ void k_pack(const float* __restrict__ W, int K1, const float* __restrict__ U,
                       __bf16* __restrict__ dst, int KH, int NCH){
  int kk0 = blockIdx.x*32, j0 = blockIdx.y*64, tid = threadIdx.x;
  __shared__ __bf16 Tl[32][72];
  {
    int r = tid>>3, cp = tid&7;
    int kk = kk0 + r;
    const float* src = (kk < K1) ? (W + (size_t)kk*G4 + j0 + cp*8)
                                 : (U + (size_t)(kk-K1)*G4 + j0 + cp*8);
    float4 v0 = *(const float4*)(src);
    float4 v1 = *(const float4*)(src+4);
    Tl[r][cp*8+0]=(__bf16)v0.x; Tl[r][cp*8+1]=(__bf16)v0.y;
    Tl[r][cp*8+2]=(__bf16)v0.z; Tl[r][cp*8+3]=(__bf16)v0.w;
    Tl[r][cp*8+4]=(__bf16)v1.x; Tl[r][cp*8+5]=(__bf16)v1.y;
    Tl[r][cp*8+6]=(__bf16)v1.z; Tl[r][cp*8+7]=(__bf16)v1.w;
  }
  __syncthreads();
  int jl = tid&63, q = tid>>6;
  __bf16 out8[8];
  #pragma unroll
  for (int i=0;i<8;i++) out8[i] = Tl[q*8+i][jl];
  int j = j0 + jl;
  int g = j>>10, gp = g>>1, gbit = g&1;
  int bi = (j&1023)>>3, jlo = j&7;
  int kh = kk0 / KH, ch = (kk0 % KH) >> 5;
  int lane = q*16 + gbit*8 + jlo;
  size_t off = ((((size_t)(bi*2+gp)*2 + kh)*NCH + ch)*64 + lane)*8;
  *(bf16x8*)(dst + off) = *(bf16x8*)out8;
}

// ---------- fused gates GEMM + LSTM cell ----------
// grid 128 blocks (8 h-dims each), 256 threads = 4 waves: (gp = w&1 -> gate pair, kh = w>>1)
template<int K, int NCH>
__global__ __launch_bounds__(256) void k_step(
    const __bf16* __restrict__ xa_in, const __bf16* __restrict__ WP,
    const float* __restrict__ bias, float* __restrict__ cst,
    __bf16* __restrict__ hout0, int stride0, int off0,
    __bf16* __restrict__ hout1, int stride1, int off1,
    float* __restrict__ houtf, int stridef, int offf)
{
  constexpr int KH = K/2;
  int bi = blockIdx.x, tid = threadIdx.x;
  int w = tid>>6, lane = tid&63;
  int gp = w&1, kh = w>>1;
  __shared__ __align__(16) __bf16 As[2][2][32][40];
  __shared__ float Gp[2][32][17];
  __shared__ float Gs[32][33];
  f32x4 acc0 = {0,0,0,0}, acc1 = {0,0,0,0};

  int sm = (tid>>2)&31, sp = tid&3, skh = tid>>7;
  const __bf16* aptr = xa_in + (size_t)sm*K + skh*KH + sp*8;
  const __bf16* bptr = WP + ((((size_t)bi*2 + gp)*2 + kh)*NCH)*512 + lane*8;
  int am = lane&15, aq = lane>>4;

  bf16x8 sreg0 = *(const bf16x8*)(aptr);
  bf16x8 breg0 = *(const bf16x8*)(bptr);
  bf16x8 sreg1 = *(const bf16x8*)(aptr + 32);
  bf16x8 breg1 = *(const bf16x8*)(bptr + 512);

  int buf = 0;
  for (int ch = 0; ch < NCH; ch++){
    *(bf16x8*)(&As[buf][skh][sm][sp*8]) = sreg0;
    __syncthreads();
    bf16x8 bcur = breg0;
    sreg0 = sreg1; breg0 = breg1;
    if (ch + 2 < NCH){
      sreg1 = *(const bf16x8*)(aptr + (size_t)(ch+2)*32);
      breg1 = *(const bf16x8*)(bptr + (size_t)(ch+2)*512);
    }
    bf16x8 a0 = *(const bf16x8*)(&As[buf][kh][am][aq*8]);
    bf16x8 a1 = *(const bf16x8*)(&As[buf][kh][am+16][aq*8]);
    acc0 = __builtin_amdgcn_mfma_f32_16x16x32_bf16(a0, bcur, acc0, 0, 0, 0);
    acc1 = __builtin_amdgcn_mfma_f32_16x16x32_bf16(a1, bcur, acc1, 0, 0, 0);
    buf ^= 1;
  }
  __syncthreads();
  if (kh == 1){
    #pragma unroll
    for (int rg=0; rg<4; rg++){
      Gp[gp][aq*4+rg][am]    = acc0[rg];
      Gp[gp][16+aq*4+rg][am] = acc1[rg];
    }
  }
  __syncthreads();
  if (kh == 0){
    #pragma unroll
    for (int rg=0; rg<4; rg++){
      Gs[aq*4+rg][gp*16+am]    = acc0[rg] + Gp[gp][aq*4+rg][am];
      Gs[16+aq*4+rg][gp*16+am] = acc1[rg] + Gp[gp][16+aq*4+rg][am];
    }
  }
  __syncthreads();
  int b = tid>>3, hd = tid&7;
  int j = bi*8 + hd;
  float gi = Gs[b][hd]     + bias[j];
  float gf = Gs[b][8+hd]   + bias[1024 + j];
  float gg = Gs[b][16+hd]  + bias[2048 + j];
  float go = Gs[b][24+hd]  + bias[3072 + j];
  float ii = sigmoidf_(gi), ff = sigmoidf_(gf), gv = tanhf(gg), oo = sigmoidf_(go);
  float cv = ff*cst[b*1024 + j] + ii*gv;
  float hv = oo*tanhf(cv);
  cst[b*1024 + j] = cv;
  hout0[(size_t)b*stride0 + off0 + j] = (__bf16)hv;
  if (hout1) hout1[(size_t)b*stride1 + off1 + j] = (__bf16)hv;
  if (houtf) houtf[(size_t)b*stridef + offf + j] = hv;
}

// ---------- attention (bf16 enc): scores -> softmax -> ctx; writes xa0 next + feats ----------
__global__ void k_attn(const __bf16* __restrict__ encb, const int* __restrict__ enc_lens,
                       float* __restrict__ featst, __bf16* __restrict__ xa0q,
                       const __bf16* __restrict__ embnext){
  int b = blockIdx.x, tid = threadIdx.x;   // 32 x 256
  __shared__ float hS[C_];
  __shared__ float sS[64];
  __shared__ float pS[64];
  #pragma unroll
  for (int i=0;i<4;i++) hS[tid + i*256] = featst[(size_t)b*2048 + tid + i*256];
  __syncthreads();
  int wv = tid >> 6, lane = tid & 63;
  for (int s = wv; s < S_; s += 4){
    const __bf16* er = encb + ((size_t)s*32 + b)*C_;
    float a = 0.f;
    #pragma unroll
    for (int half = 0; half < 2; half++){
      int k = lane*8 + half*512;
      bf16x8 e8 = *(const bf16x8*)(er + k);
      #pragma unroll
      for (int u=0;u<8;u++) a += b2f(e8[u]) * hS[k+u];
    }
    #pragma unroll
    for (int off=32; off>0; off>>=1) a += __shfl_down(a, off);
    if (lane == 0) sS[s] = a;
  }
  __syncthreads();
  if (tid < 64){
    int len = enc_lens[b];
    float sc = (tid < len && tid < S_) ? sS[tid] : -1e30f;
    float m = sc;
    #pragma unroll
    for (int off=32; off>0; off>>=1) m = fmaxf(m, __shfl_xor(m, off));
    float e = expf(sc - m);
    float ssum = e;
    #pragma unroll
    for (int off=32; off>0; off>>=1) ssum += __shfl_xor(ssum, off);
    pS[tid] = e / ssum;
  }
  __syncthreads();
  for (int c2 = tid; c2 < C_; c2 += 256){
    float a = 0.f;
    for (int s2 = 0; s2 < S_; s2++) a += pS[s2] * b2f(encb[((size_t)s2*32 + b)*C_ + c2]);
    xa0q[(size_t)b*2560 + 512 + c2] = (__bf16)a;
    featst[(size_t)b*2048 + 1024 + c2] = a;
  }
  if (embnext){
    for (int c2 = tid; c2 < 512; c2 += 256)
      xa0q[(size_t)b*2560 + c2] = embnext[(size_t)b*512 + c2];
  }
}

// ---------- hproj = tanh(feats @ Wo + bo) ----------
__global__ void k_hproj(const float* __restrict__ feats, const float* __restrict__ Wo,
                        const float* __restrict__ bo, float* __restrict__ hp){
  int nt = blockIdx.x, jt = blockIdx.y, tid = threadIdx.x;
  __shared__ float Fs[32][36];
  __shared__ float Ws[32*128];
  int jg = tid & 31, bg = tid >> 5;
  float4 acc[4];
  #pragma unroll
  for (int i=0;i<4;i++) acc[i] = make_float4(0.f,0.f,0.f,0.f);
  for (int kc = 0; kc < 2048; kc += 32){
    { int b = tid & 31, kq = tid >> 5;
      *(float4*)(&Fs[b][kq*4]) =
        *(const float4*)(feats + ((size_t)nt*32 + b)*2048 + kc + kq*4); }
    #pragma unroll
    for (int i2=0;i2<4;i2++){
      int idx = i2*256 + tid;
      int k = idx >> 5, jq = idx & 31;
      *(float4*)(&Ws[k*128 + jq*4]) =
        *(const float4*)(Wo + (size_t)(kc + k)*EMB_ + jt*128 + jq*4);
    }
    __syncthreads();
    #pragma unroll
    for (int k=0;k<32;k++){
      float4 w4 = *(const float4*)(&Ws[k*128 + jg*4]);
      #pragma unroll
      for (int i=0;i<4;i++){
        float xv = Fs[bg*4 + i][k];
        acc[i].x += xv*w4.x; acc[i].y += xv*w4.y;
        acc[i].z += xv*w4.z; acc[i].w += xv*w4.w;
      }
    }
    __syncthreads();
  }
  float4 b4 = *(const float4*)(bo + jt*128 + jg*4);
  #pragma unroll
  for (int i=0;i<4;i++){
    int b = bg*4 + i;
    float4 v;
    v.x = tanhf(acc[i].x + b4.x); v.y = tanhf(acc[i].y + b4.y);
    v.z = tanhf(acc[i].z + b4.z); v.w = tanhf(acc[i].w + b4.w);
    *(float4*)(hp + ((size_t)nt*32 + b)*EMB_ + jt*128 + jg*4) = v;
  }
}

// ---------- r = hproj @ P^T ----------
__global__ void k_rproj(const float* __restrict__ hp, const float* __restrict__ P,
                        float* __restrict__ r){
  int n = blockIdx.x, tid = threadIdx.x;   // 1504 x 128
  __shared__ float hS[EMB_];
  *(float4*)(hS + tid*4) = *(const float4*)(hp + (size_t)n*EMB_ + tid*4);
  __syncthreads();
  float a = 0.f;
  for (int e = 0; e < EMB_; e += 4){
    float4 p4 = *(const float4*)(P + (size_t)tid*EMB_ + e);
    a += p4.x*hS[e] + p4.y*hS[e+1] + p4.z*hS[e+2] + p4.w*hS[e+3];
  }
  r[(size_t)n*RANK_ + tid] = a;
}

// ---------- vocab GEMM + online LSE partials ----------
__global__ void k_vocab(const float* __restrict__ r, const float* __restrict__ E,
                        const int* __restrict__ tok,
                        float* __restrict__ mpart, float* __restrict__ lpart,
                        float* __restrict__ lablog){
  int nt = blockIdx.x, vc = blockIdx.y, tid = threadIdx.x;
  __shared__ float rS[32][132];
  __shared__ float eS[16*260];
  #pragma unroll
  for (int i=0;i<4;i++){
    int idx = i*256 + tid; int nl = idx >> 5, kq = idx & 31;
    *(float4*)(&rS[nl][kq*4]) = *(const float4*)(r + ((size_t)nt*32 + nl)*RANK_ + kq*4);
  }
  int ng = tid & 3, vg = tid >> 2;
  float acc[8][4];
  #pragma unroll
  for (int i=0;i<8;i++)
    #pragma unroll
    for (int j=0;j<4;j++) acc[i][j] = 0.f;
  int vbase = vc*256;
  for (int kc = 0; kc < 8; kc++){
    __syncthreads();
    #pragma unroll
    for (int i=0;i<4;i++){
      int idx = i*256 + tid; int vl = idx >> 2, kq = idx & 3;
      float4 ev = *(const float4*)(E + (size_t)(vbase + vl)*RANK_ + kc*16 + kq*4);
      eS[(kq*4+0)*260 + vl] = ev.x;
      eS[(kq*4+1)*260 + vl] = ev.y;
      eS[(kq*4+2)*260 + vl] = ev.z;
      eS[(kq*4+3)*260 + vl] = ev.w;
    }
    __syncthreads();
    #pragma unroll
    for (int k=0;k<16;k++){
      float4 e4 = *(const float4*)(&eS[k*260 + vg*4]);
      int gk = kc*16 + k;
      #pragma unroll
      for (int i=0;i<8;i++){
        float rv = rS[ng*8 + i][gk];
        acc[i][0] += rv*e4.x; acc[i][1] += rv*e4.y;
        acc[i][2] += rv*e4.z; acc[i][3] += rv*e4.w;
      }
    }
  }
  __syncthreads();
  float* mred = eS;
  float* lred = eS + 2080;
  #pragma unroll
  for (int i=0;i<8;i++){
    int nl = ng*8 + i;
    int n = nt*32 + nl;
    int lbl = tok[nl*T_ + nt + 1];
    float m = fmaxf(fmaxf(acc[i][0], acc[i][1]), fmaxf(acc[i][2], acc[i][3]));
    float l = expf(acc[i][0]-m) + expf(acc[i][1]-m) + expf(acc[i][2]-m) + expf(acc[i][3]-m);
    int lo = lbl - (vbase + vg*4);
    if (lo >= 0 && lo < 4) lablog[n] = acc[i][lo];
    mred[nl*65 + vg] = m;
    lred[nl*65 + vg] = l;
  }
  __syncthreads();
  if (tid < 32){
    float M = -1e30f;
    for (int v=0; v<64; v++) M = fmaxf(M, mred[tid*65 + v]);
    float L = 0.f;
    for (int v=0; v<64; v++) L += lred[tid*65 + v]*expf(mred[tid*65 + v] - M);
    int n = nt*32 + tid;
    mpart[(size_t)n*125 + vc] = M;
    lpart[(size_t)n*125 + vc] = L;
  }
}

// ---------- final loss ----------
__global__ void k_loss(const float* __restrict__ mpart, const float* __restrict__ lpart,
                       const float* __restrict__ lablog, const int* __restrict__ tgt_lens,
                       float* __restrict__ out){
  int tid = threadIdx.x;
  float local = 0.f;
  for (int n = tid; n < TS*32; n += 256){
    int t = n >> 5, b = n & 31;
    if (t < tgt_lens[b] - 1){
      const float* mp = mpart + (size_t)n*125;
      const float* lp = lpart + (size_t)n*125;
      float M = -1e30f;
      for (int c2=0;c2<125;c2++) M = fmaxf(M, mp[c2]);
      float L = 0.f;
      for (int c2=0;c2<125;c2++) L += lp[c2]*expf(mp[c2] - M);
      local += (M + logf(L)) - lablog[n];
    }
  }
  __shared__ float red[256];
  red[tid] = local; __syncthreads();
  for (int s2 = 128; s2 > 0; s2 >>= 1){
    if (tid < s2) red[tid] += red[tid + s2];
    __syncthreads();
  }
  if (tid == 0) out[0] = red[0];
}

extern "C" void kernel_launch(void* const* d_in, const int* in_sizes, int n_in,
                              void* d_out, int out_size, void* d_ws, size_t ws_size,
                              hipStream_t stream){
  const float* enc      = (const float*)d_in[0];
  const float* es       = (const float*)d_in[1];
  const int*   tok      = (const int*)  d_in[2];
  const int*   enc_lens = (const int*)  d_in[3];
  const int*   tgt_lens = (const int*)  d_in[4];
  const float* E        = (const float*)d_in[5];
  const float* P        = (const float*)d_in[6];
  const float* W0       = (const float*)d_in[7];
  const float* U0       = (const float*)d_in[8];
  const float* b0       = (const float*)d_in[9];
  const float* W1       = (const float*)d_in[10];
  const float* U1       = (const float*)d_in[11];
  const float* b1       = (const float*)d_in[12];
  const float* Wo       = (const float*)d_in[13];
  const float* bo       = (const float*)d_in[14];
  float* out = (float*)d_out;

  float* fb = (float*)d_ws;
  size_t fo = 0;
  float* feats = fb + fo; fo += (size_t)TS*32*2048;
  float* hp    = fb + fo; fo += (size_t)TS*32*EMB_;
  float* r     = fb + fo; fo += (size_t)TS*32*RANK_;
  float* mpart = fb + fo; fo += (size_t)TS*32*125;
  float* lpart = fb + fo; fo += (size_t)TS*32*125;
  float* lab   = fb + fo; fo += (size_t)TS*32;
  float* c0    = fb + fo; fo += 32*H_;
  float* c1    = fb + fo; fo += 32*H_;
  __bf16* bb = (__bf16*)(fb + fo);
  size_t bo2 = 0;
  __bf16* WP0  = bb + bo2; bo2 += (size_t)4096*2560;
  __bf16* WP1  = bb + bo2; bo2 += (size_t)4096*2048;
  __bf16* encb = bb + bo2; bo2 += (size_t)S_*32*C_;
  __bf16* embb = bb + bo2; bo2 += (size_t)TS*32*EMB_;
  __bf16* xa0[2]; xa0[0] = bb + bo2; bo2 += (size_t)32*2560;
                  xa0[1] = bb + bo2; bo2 += (size_t)32*2560;
  __bf16* xa1[2]; xa1[0] = bb + bo2; bo2 += (size_t)32*2048;
                  xa1[1] = bb + bo2; bo2 += (size_t)32*2048;

  k_init<<<128, 256, 0, stream>>>(es, xa0[0], xa1[0], c0, c1);
  k_cvt<<<(S_*32*C_/4 + 255)/256, 256, 0, stream>>>(enc, encb, S_*32*C_);
  k_embed<<<TS*32, 128, 0, stream>>>(E, P, tok, embb, xa0[0]);
  k_pack<<<dim3(80,64), 256, 0, stream>>>(W0, 1536, U0, WP0, 1280, 40);
  k_pack<<<dim3(64,64), 256, 0, stream>>>(W1, 1024, U1, WP1, 1024, 32);

  for (int t = 0; t < TS; t++){
    int p = t & 1, q = p ^ 1;
    k_step<2560,40><<<128, 256, 0, stream>>>(xa0[p], WP0, b0, c0,
        xa1[p], 2048, 0,          // h0 -> xa1 cur [0:1024]
        xa0[q], 2560, 1536,       // h0 -> xa0 next [1536:2560]
        (float*)nullptr, 0, 0);
    k_step<2048,32><<<128, 256, 0, stream>>>(xa1[p], WP1, b1, c1,
        xa1[q], 2048, 1024,       // h1 -> xa1 next [1024:2048]
        (__bf16*)nullptr, 0, 0,
        feats + (size_t)t*32*2048, 2048, 0);
    k_attn<<<32, 256, 0, stream>>>(encb, enc_lens, feats + (size_t)t*32*2048,
        xa0[q], (t+1 < TS) ? (embb + (size_t)(t+1)*32*EMB_) : (const __bf16*)nullptr);
  }

  k_hproj<<<dim3(TS,4), 256, 0, stream>>>(feats, Wo, bo, hp);
  k_rproj<<<TS*32, 128, 0, stream>>>(hp, P, r);
  k_vocab<<<dim3(TS,125), 256, 0, stream>>>(r, E, tok, mpart, lpart, lab);
  k_loss<<<1, 256, 0, stream>>>(mpart, lpart, lab, tgt_lens, out);
}